// Round 15
// baseline (118.824 us; speedup 1.0000x reference)
//
#include <hip/hip_runtime.h>
#include <stdint.h>

#define NV 16
#define NC 16
#define NH 1024
#define NW 1024
#define NRM 8
#define NRD 4

typedef __attribute__((ext_vector_type(4))) _Float16 f16x4;
typedef __attribute__((ext_vector_type(2))) __fp16 fp16x2_raw;
typedef __attribute__((ext_vector_type(4))) float f32x4;

#define MFMA16(a, b, c) __builtin_amdgcn_mfma_f32_16x16x16f16((a), (b), (c), 0, 0, 0)

// f32 pair -> packed f16 (RTZ)
__device__ __forceinline__ uint32_t pkh(float a, float b) {
    fp16x2_raw h = __builtin_amdgcn_cvt_pkrtz(a, b);
    return __builtin_bit_cast(uint32_t, h);
}

__device__ __forceinline__ f16x4 mk4(uint32_t lo, uint32_t hi) {
    union { uint32_t u[2]; f16x4 v; } t;
    t.u[0] = lo; t.u[1] = hi;
    return t.v;
}

// acc += dot2(f16x2(u), f16x2(v))  -- full-rate f16 MAC pair with f32 accumulate
#define DOT2(acc, u, v) \
    asm("v_dot2_f32_f16 %0, %1, %2, %0" : "+v"(acc) : "v"(u), "v"(v))

// atan2 emitting REVOLUTIONS (atan2/2pi)
__device__ __forceinline__ float atan2_rev(float y, float x) {
    float ax = fabsf(x), ay = fabsf(y);
    float mx = fmaxf(ax, ay), mn = fminf(ax, ay);
    float a = mn * __builtin_amdgcn_rcpf(mx);
    float s = a * a;
    float p =              -0.00186549f;
    p = fmaf(p, s,  0.00838003f);
    p = fmaf(p, s, -0.01852970f);
    p = fmaf(p, s,  0.03080340f);
    p = fmaf(p, s, -0.05294381f);
    p = fmaf(p, s,  0.15915132f);
    p = p * a;
    float t = (ay > ax) ? (0.25f - p) : p;
    t = (x < 0.0f) ? (0.5f - t) : t;
    return (y < 0.0f) ? -t : t;
}

// exponent-domain constants: A=0.5*wr  B=wi*2pi*log2e  C=wr  D=wi*ln2/(4pi)
#define K_B 9.06472028f
#define K_D 0.05516054f

// -------- pre-pass: repack mod_v/del_v to [c][w][r] dual-form f16 --------
__global__ __launch_bounds__(256)
void repack_v(const float* __restrict__ mod_v, const float* __restrict__ del_v,
              uint32_t* __restrict__ mvT2, uint32_t* __restrict__ dvT2)
{
    const int idx = blockIdx.x * 256 + threadIdx.x;
    if (idx < NC * NRM * NW) {                       // 131072 mod items
        const int c = idx >> 13, r = (idx >> 10) & 7, w = idx & 1023;
        const float2 v = reinterpret_cast<const float2*>(mod_v)[(c * NRM + r) * NW + w];
        uint2* dst = reinterpret_cast<uint2*>(mvT2) + (c * NW + w) * NRM + r;
        *dst = make_uint2(pkh(v.x, -v.y), pkh(v.y, v.x));
    } else {                                         // 65536 del items
        const int t = idx - NC * NRM * NW;
        const int c = t >> 12, r = (t >> 10) & 3, w = t & 1023;
        const float2 v = reinterpret_cast<const float2*>(del_v)[(c * NRD + r) * NW + w];
        uint2* dst = reinterpret_cast<uint2*>(dvT2) + (c * NW + w) * NRD + r;
        *dst = make_uint2(pkh(v.x, -v.y), pkh(v.y, v.x));
    }
}

struct V6h { uint4 L0, L1, L2, L3, D0, D1; };   // mod ranks 0-7, del ranks 0-3 (dual-form f16)

template <bool TR>
__device__ __forceinline__ V6h load_vh(const uint32_t* __restrict__ mvT2,
                                       const uint32_t* __restrict__ dvT2,
                                       const float* __restrict__ mod_v,
                                       const float* __restrict__ del_v,
                                       int c, int w)
{
    V6h r;
    if (TR) {
        const uint4* mp = reinterpret_cast<const uint4*>(mvT2) + (c * NW + w) * 4;
        r.L0 = mp[0]; r.L1 = mp[1]; r.L2 = mp[2]; r.L3 = mp[3];
        const uint4* dp = reinterpret_cast<const uint4*>(dvT2) + (c * NW + w) * 2;
        r.D0 = dp[0]; r.D1 = dp[1];
    } else {
        const float2* m = reinterpret_cast<const float2*>(mod_v) + c * NRM * NW + w;
        float2 a0 = m[0], a1 = m[NW], a2 = m[2*NW], a3 = m[3*NW];
        float2 a4 = m[4*NW], a5 = m[5*NW], a6 = m[6*NW], a7 = m[7*NW];
        r.L0 = make_uint4(pkh(a0.x,-a0.y), pkh(a0.y,a0.x), pkh(a1.x,-a1.y), pkh(a1.y,a1.x));
        r.L1 = make_uint4(pkh(a2.x,-a2.y), pkh(a2.y,a2.x), pkh(a3.x,-a3.y), pkh(a3.y,a3.x));
        r.L2 = make_uint4(pkh(a4.x,-a4.y), pkh(a4.y,a4.x), pkh(a5.x,-a5.y), pkh(a5.y,a5.x));
        r.L3 = make_uint4(pkh(a6.x,-a6.y), pkh(a6.y,a6.x), pkh(a7.x,-a7.y), pkh(a7.y,a7.x));
        const float2* d = reinterpret_cast<const float2*>(del_v) + c * NRD * NW + w;
        float2 b0 = d[0], b1 = d[NW], b2 = d[2*NW], b3 = d[3*NW];
        r.D0 = make_uint4(pkh(b0.x,-b0.y), pkh(b0.y,b0.x), pkh(b1.x,-b1.y), pkh(b1.y,b1.x));
        r.D1 = make_uint4(pkh(b2.x,-b2.y), pkh(b2.y,b2.x), pkh(b3.x,-b3.y), pkh(b3.y,b3.x));
    }
    return r;
}

// lane l = (col = l&15, kb = l>>4): computes P[c = 4*kb+j][pixel col] for j=0..3
// = its MFMA B-fragment directly in registers. Recon via v_dot2_f32_f16.
// [R12 passing structure; launch_bounds min-waves raised 4->8 for latency hiding:
//  VGPR was 44 (<=64 cap), LDS 1.5 KB -- nothing else limits 8 waves/SIMD]
template <bool TR>
__global__ __launch_bounds__(256, 8)
void fused_kernel(const float* __restrict__ base, const float* __restrict__ mod_u,
                  const float* __restrict__ mod_v, const float* __restrict__ del_u,
                  const float* __restrict__ del_v, const float* __restrict__ exp_base,
                  const float* __restrict__ exp_mod, const float* __restrict__ exp_del,
                  const float* __restrict__ bias_, const float* __restrict__ scale_,
                  const float* __restrict__ coef, float* __restrict__ out,
                  const uint32_t* __restrict__ mvT2, const uint32_t* __restrict__ dvT2)
{
    __shared__ uint4 uA16[NC][2][2];   // mod_u packed f16 (ur,ui)/rank; 1 KB; slot ^= (c>>2)&1
    __shared__ uint4 uD16[NC][2];      // del_u packed f16; 512 B

    const int tid  = threadIdx.x;
    const int lane = tid & 63;
    const int wv   = tid >> 6;
    const int col  = lane & 15;
    const int kb   = lane >> 4;                    // c-block / v-block
    const int bw   = (int)(blockIdx.x & 15);
    const int hp   = (int)(blockIdx.x >> 4);
    const int h0   = hp * 2;
    const int w    = (bw << 6) | (wv << 4) | col;

    // ---------- cooperative preload + f16 pack of u-tables ----------
    {
        if (tid < 64) {                            // uA: 16c x 2rr x 2slots(4 ranks)
            const int c = tid >> 2, rr = (tid >> 1) & 1, k = tid & 1;
            const float4 a = *reinterpret_cast<const float4*>(
                mod_u + ((c * NH) + (h0 + rr)) * (NRM * 2) + k * 8);
            const float4 b = *reinterpret_cast<const float4*>(
                mod_u + ((c * NH) + (h0 + rr)) * (NRM * 2) + k * 8 + 4);
            uA16[c][rr][k ^ ((c >> 2) & 1)] =
                make_uint4(pkh(a.x, a.y), pkh(a.z, a.w), pkh(b.x, b.y), pkh(b.z, b.w));
        } else if (tid < 96) {                     // uD: 16c x 2rr (4 ranks)
            const int t = tid - 64;
            const int c = t >> 1, rr = t & 1;
            const float4 a = *reinterpret_cast<const float4*>(
                del_u + ((c * NH) + (h0 + rr)) * (NRD * 2));
            const float4 b = *reinterpret_cast<const float4*>(
                del_u + ((c * NH) + (h0 + rr)) * (NRD * 2) + 4);
            uD16[c][rr] =
                make_uint4(pkh(a.x, a.y), pkh(a.z, a.w), pkh(b.x, b.y), pkh(b.z, b.w));
        }
    }
    __syncthreads();

    // ---------- per-lane A-fragments + bias-const accumulator seed ----------
    const int vv = col;
    const int c0 = kb << 2;

    const float4 cfa = *reinterpret_cast<const float4*>(coef   + (vv * NC + c0) * 2);
    const float4 cfb = *reinterpret_cast<const float4*>(coef   + (vv * NC + c0) * 2 + 4);
    const float4 sca = *reinterpret_cast<const float4*>(scale_ + c0 * 2);
    const float4 scb = *reinterpret_cast<const float4*>(scale_ + c0 * 2 + 4);
    const float4 bia = *reinterpret_cast<const float4*>(bias_  + c0 * 2);
    const float4 bib = *reinterpret_cast<const float4*>(bias_  + c0 * 2 + 4);

    float c2r0 = cfa.x*sca.x - cfa.y*sca.y, c2i0 = cfa.x*sca.y + cfa.y*sca.x;
    float c2r1 = cfa.z*sca.z - cfa.w*sca.w, c2i1 = cfa.z*sca.w + cfa.w*sca.z;
    float c2r2 = cfb.x*scb.x - cfb.y*scb.y, c2i2 = cfb.x*scb.y + cfb.y*scb.x;
    float c2r3 = cfb.z*scb.z - cfb.w*scb.w, c2i3 = cfb.z*scb.w + cfb.w*scb.z;

    const f16x4 Ar = mk4(pkh(c2r0, c2r1), pkh(c2r2, c2r3));
    const f16x4 Ai = mk4(pkh(c2i0, c2i1), pkh(c2i2, c2i3));
    const f16x4 An = mk4(pkh(-c2i0, -c2i1), pkh(-c2i2, -c2i3));

    const f16x4 Kr = mk4(pkh(cfa.x, cfa.z), pkh(cfb.x, cfb.z));
    const f16x4 Ki = mk4(pkh(cfa.y, cfa.w), pkh(cfb.y, cfb.w));
    const f16x4 Kn = mk4(pkh(-cfa.y, -cfa.w), pkh(-cfb.y, -cfb.w));

    const f16x4 Bbr = mk4(pkh(bia.x, bia.z), pkh(bib.x, bib.z));
    const f16x4 Bbi = mk4(pkh(bia.y, bia.w), pkh(bib.y, bib.w));

    const f32x4 zero4 = {0.f, 0.f, 0.f, 0.f};
    const f32x4 cr4 = MFMA16(Kr, Bbr, MFMA16(Kn, Bbi, zero4));
    const f32x4 ci4 = MFMA16(Ki, Bbr, MFMA16(Kr, Bbi, zero4));

    // ---------- base contribution in exponent domain, per row ----------
    const float ebr = exp_base[0], ebi = exp_base[1];
    const float Ab = 0.5f * ebr, Bb = ebi * K_B, Cb = ebr, Db = ebi * K_D;
    float berr[2], beir[2];
    {
        const float2 b0 = reinterpret_cast<const float2*>(base)[(h0    ) * NW + w];
        const float2 b1 = reinterpret_cast<const float2*>(base)[(h0 + 1) * NW + w];
        const float L2b0 = __builtin_amdgcn_logf(fmaf(b0.x, b0.x, b0.y * b0.y));
        const float th0  = atan2_rev(b0.y, b0.x);
        const float L2b1 = __builtin_amdgcn_logf(fmaf(b1.x, b1.x, b1.y * b1.y));
        const float th1  = atan2_rev(b1.y, b1.x);
        berr[0] = fmaf(Ab, L2b0, -Bb * th0);
        beir[0] = fmaf(Cb, th0,   Db * L2b0);
        berr[1] = fmaf(Ab, L2b1, -Bb * th1);
        beir[1] = fmaf(Cb, th1,   Db * L2b1);
    }

    // ---------- main loop: this lane's 4 c-values = its B-fragment ----------
    float Pr[2][4], Pi[2][4];

    #pragma unroll
    for (int j = 0; j < 4; ++j) {
        const int c = c0 | j;
        const V6h cur = load_vh<TR>(mvT2, dvT2, mod_v, del_v, c, w);

        const float2 em = reinterpret_cast<const float2*>(exp_mod)[c];
        const float2 ed = reinterpret_cast<const float2*>(exp_del)[c];
        const float kmA = 0.5f * em.x, kmB = em.y * K_B, kmC = em.x, kmD = em.y * K_D;
        const float kdA = 0.5f * ed.x, kdB = ed.y * K_B, kdC = ed.x, kdD = ed.y * K_D;

        #pragma unroll
        for (int rr = 0; rr < 2; ++rr) {
            const uint4 qa0 = uA16[c][rr][0 ^ ((c >> 2) & 1)];   // ranks 0-3
            const uint4 qa1 = uA16[c][rr][1 ^ ((c >> 2) & 1)];   // ranks 4-7
            const uint4 qd  = uD16[c][rr];                       // del ranks 0-3

            float tr = 0.f, ti = 0.f;
            DOT2(tr, qa0.x, cur.L0.x); DOT2(ti, qa0.x, cur.L0.y);
            DOT2(tr, qa0.y, cur.L0.z); DOT2(ti, qa0.y, cur.L0.w);
            DOT2(tr, qa0.z, cur.L1.x); DOT2(ti, qa0.z, cur.L1.y);
            DOT2(tr, qa0.w, cur.L1.z); DOT2(ti, qa0.w, cur.L1.w);
            DOT2(tr, qa1.x, cur.L2.x); DOT2(ti, qa1.x, cur.L2.y);
            DOT2(tr, qa1.y, cur.L2.z); DOT2(ti, qa1.y, cur.L2.w);
            DOT2(tr, qa1.z, cur.L3.x); DOT2(ti, qa1.z, cur.L3.y);
            DOT2(tr, qa1.w, cur.L3.z); DOT2(ti, qa1.w, cur.L3.w);

            float dr = 0.f, di = 0.f;
            DOT2(dr, qd.x, cur.D0.x); DOT2(di, qd.x, cur.D0.y);
            DOT2(dr, qd.y, cur.D0.z); DOT2(di, qd.y, cur.D0.w);
            DOT2(dr, qd.z, cur.D1.x); DOT2(di, qd.z, cur.D1.y);
            DOT2(dr, qd.w, cur.D1.z); DOT2(di, qd.w, cur.D1.w);

            // mod power, base-folded: pb*pm = exp2(er2)·cis(2pi·eir)
            const float L2m = __builtin_amdgcn_logf(fmaf(tr, tr, ti * ti));
            const float thm = atan2_rev(ti, tr);
            const float er2 = fmaf(kmA, L2m, fmaf(-kmB, thm, berr[rr]));
            const float eir = fmaf(kmC, thm, fmaf(kmD, L2m, beir[rr]));
            const float mm  = __builtin_amdgcn_exp2f(er2);
            const float fm  = __builtin_amdgcn_fractf(eir);
            const float cv  = __builtin_amdgcn_cosf(fm);
            const float sv  = __builtin_amdgcn_sinf(fm);

            // del power
            const float L2d = __builtin_amdgcn_logf(fmaf(dr, dr, di * di));
            const float thd = atan2_rev(di, dr);
            const float er2d = fmaf(kdA, L2d, -kdB * thd);
            const float eird = fmaf(kdC, thd,  kdD * L2d);
            const float md  = __builtin_amdgcn_exp2f(er2d);
            const float fd  = __builtin_amdgcn_fractf(eird);
            const float cvd = __builtin_amdgcn_cosf(fd);
            const float svd = __builtin_amdgcn_sinf(fd);

            Pr[rr][j] = fmaf(mm, cv, md * cvd);
            Pi[rr][j] = fmaf(mm, sv, md * svd);
        }
    }

    // ---------- MFMA einsum straight from registers ----------
    float2* outp = reinterpret_cast<float2*>(out);
    #pragma unroll
    for (int rr = 0; rr < 2; ++rr) {
        const f16x4 Brf = mk4(pkh(Pr[rr][0], Pr[rr][1]), pkh(Pr[rr][2], Pr[rr][3]));
        const f16x4 Bif = mk4(pkh(Pi[rr][0], Pi[rr][1]), pkh(Pi[rr][2], Pi[rr][3]));
        const f32x4 Dr = MFMA16(Ar, Brf, MFMA16(An, Bif, cr4));
        const f32x4 Di = MFMA16(Ai, Brf, MFMA16(Ar, Bif, ci4));
        const int bidx = (h0 + rr) * NW + w;
        #pragma unroll
        for (int jj = 0; jj < 4; ++jj) {
            const int v = (kb << 2) + jj;
            outp[v * (NH * NW) + bidx] = make_float2(Dr[jj], Di[jj]);
        }
    }
}

extern "C" void kernel_launch(void* const* d_in, const int* in_sizes, int n_in,
                              void* d_out, int out_size, void* d_ws, size_t ws_size,
                              hipStream_t stream) {
    const float* base     = (const float*)d_in[0];
    const float* mod_u    = (const float*)d_in[1];
    const float* mod_v    = (const float*)d_in[2];
    const float* del_u    = (const float*)d_in[3];
    const float* del_v    = (const float*)d_in[4];
    const float* exp_base = (const float*)d_in[5];
    const float* exp_mod  = (const float*)d_in[6];
    const float* exp_del  = (const float*)d_in[7];
    const float* bias_    = (const float*)d_in[8];
    const float* scale_   = (const float*)d_in[9];
    const float* coef     = (const float*)d_in[10];
    float* outp = (float*)d_out;

    const int blocks = (NH / 2) * (NW / 64);               // 8192
    const size_t mvT2_u32 = (size_t)NC * NW * NRM * 2;     // 1 MB
    const size_t dvT2_u32 = (size_t)NC * NW * NRD * 2;     // 0.5 MB
    const size_t need = (mvT2_u32 + dvT2_u32) * sizeof(uint32_t);

    if (ws_size >= need) {
        uint32_t* mvT2 = (uint32_t*)d_ws;
        uint32_t* dvT2 = mvT2 + mvT2_u32;
        const int rp_items = NC * NRM * NW + NC * NRD * NW;     // 196608
        repack_v<<<rp_items / 256, 256, 0, stream>>>(mod_v, del_v, mvT2, dvT2);
        fused_kernel<true><<<blocks, 256, 0, stream>>>(base, mod_u, mod_v, del_u, del_v,
                                                       exp_base, exp_mod, exp_del,
                                                       bias_, scale_, coef, outp, mvT2, dvT2);
    } else {
        fused_kernel<false><<<blocks, 256, 0, stream>>>(base, mod_u, mod_v, del_u, del_v,
                                                        exp_base, exp_mod, exp_del,
                                                        bias_, scale_, coef, outp,
                                                        (const uint32_t*)nullptr, (const uint32_t*)nullptr);
    }
}

// Round 16
// 90.791 us; speedup vs baseline: 1.3088x; 1.3088x over previous
//
#include <hip/hip_runtime.h>
#include <stdint.h>

#define NV 16
#define NC 16
#define NH 1024
#define NW 1024
#define NRM 8
#define NRD 4
#define HPB 4   // row-pairs per block

typedef __attribute__((ext_vector_type(4))) _Float16 f16x4;
typedef __attribute__((ext_vector_type(2))) __fp16 fp16x2_raw;
typedef __attribute__((ext_vector_type(4))) float f32x4;

#define MFMA16(a, b, c) __builtin_amdgcn_mfma_f32_16x16x16f16((a), (b), (c), 0, 0, 0)

// f32 pair -> packed f16 (RTZ)
__device__ __forceinline__ uint32_t pkh(float a, float b) {
    fp16x2_raw h = __builtin_amdgcn_cvt_pkrtz(a, b);
    return __builtin_bit_cast(uint32_t, h);
}

__device__ __forceinline__ f16x4 mk4(uint32_t lo, uint32_t hi) {
    union { uint32_t u[2]; f16x4 v; } t;
    t.u[0] = lo; t.u[1] = hi;
    return t.v;
}

// acc += dot2(f16x2(u), f16x2(v))  -- full-rate f16 MAC pair with f32 accumulate
#define DOT2(acc, u, v) \
    asm("v_dot2_f32_f16 %0, %1, %2, %0" : "+v"(acc) : "v"(u), "v"(v))

// atan2 emitting REVOLUTIONS (atan2/2pi)
__device__ __forceinline__ float atan2_rev(float y, float x) {
    float ax = fabsf(x), ay = fabsf(y);
    float mx = fmaxf(ax, ay), mn = fminf(ax, ay);
    float a = mn * __builtin_amdgcn_rcpf(mx);
    float s = a * a;
    float p =              -0.00186549f;
    p = fmaf(p, s,  0.00838003f);
    p = fmaf(p, s, -0.01852970f);
    p = fmaf(p, s,  0.03080340f);
    p = fmaf(p, s, -0.05294381f);
    p = fmaf(p, s,  0.15915132f);
    p = p * a;
    float t = (ay > ax) ? (0.25f - p) : p;
    t = (x < 0.0f) ? (0.5f - t) : t;
    return (y < 0.0f) ? -t : t;
}

// exponent-domain constants: A=0.5*wr  B=wi*2pi*log2e  C=wr  D=wi*ln2/(4pi)
#define K_B 9.06472028f
#define K_D 0.05516054f

// -------- pre-pass: repack mod_v/del_v to [c][w][r] dual-form f16 --------
__global__ __launch_bounds__(256)
void repack_v(const float* __restrict__ mod_v, const float* __restrict__ del_v,
              uint32_t* __restrict__ mvT2, uint32_t* __restrict__ dvT2)
{
    const int idx = blockIdx.x * 256 + threadIdx.x;
    if (idx < NC * NRM * NW) {                       // 131072 mod items
        const int c = idx >> 13, r = (idx >> 10) & 7, w = idx & 1023;
        const float2 v = reinterpret_cast<const float2*>(mod_v)[(c * NRM + r) * NW + w];
        uint2* dst = reinterpret_cast<uint2*>(mvT2) + (c * NW + w) * NRM + r;
        *dst = make_uint2(pkh(v.x, -v.y), pkh(v.y, v.x));
    } else {                                         // 65536 del items
        const int t = idx - NC * NRM * NW;
        const int c = t >> 12, r = (t >> 10) & 3, w = t & 1023;
        const float2 v = reinterpret_cast<const float2*>(del_v)[(c * NRD + r) * NW + w];
        uint2* dst = reinterpret_cast<uint2*>(dvT2) + (c * NW + w) * NRD + r;
        *dst = make_uint2(pkh(v.x, -v.y), pkh(v.y, v.x));
    }
}

struct V6h { uint4 L0, L1, L2, L3, D0, D1; };   // mod ranks 0-7, del ranks 0-3 (dual-form f16)

template <bool TR>
__device__ __forceinline__ V6h load_vh(const uint32_t* __restrict__ mvT2,
                                       const uint32_t* __restrict__ dvT2,
                                       const float* __restrict__ mod_v,
                                       const float* __restrict__ del_v,
                                       int c, int w)
{
    V6h r;
    if (TR) {
        const uint4* mp = reinterpret_cast<const uint4*>(mvT2) + (c * NW + w) * 4;
        r.L0 = mp[0]; r.L1 = mp[1]; r.L2 = mp[2]; r.L3 = mp[3];
        const uint4* dp = reinterpret_cast<const uint4*>(dvT2) + (c * NW + w) * 2;
        r.D0 = dp[0]; r.D1 = dp[1];
    } else {
        const float2* m = reinterpret_cast<const float2*>(mod_v) + c * NRM * NW + w;
        float2 a0 = m[0], a1 = m[NW], a2 = m[2*NW], a3 = m[3*NW];
        float2 a4 = m[4*NW], a5 = m[5*NW], a6 = m[6*NW], a7 = m[7*NW];
        r.L0 = make_uint4(pkh(a0.x,-a0.y), pkh(a0.y,a0.x), pkh(a1.x,-a1.y), pkh(a1.y,a1.x));
        r.L1 = make_uint4(pkh(a2.x,-a2.y), pkh(a2.y,a2.x), pkh(a3.x,-a3.y), pkh(a3.y,a3.x));
        r.L2 = make_uint4(pkh(a4.x,-a4.y), pkh(a4.y,a4.x), pkh(a5.x,-a5.y), pkh(a5.y,a5.x));
        r.L3 = make_uint4(pkh(a6.x,-a6.y), pkh(a6.y,a6.x), pkh(a7.x,-a7.y), pkh(a7.y,a7.x));
        const float2* d = reinterpret_cast<const float2*>(del_v) + c * NRD * NW + w;
        float2 b0 = d[0], b1 = d[NW], b2 = d[2*NW], b3 = d[3*NW];
        r.D0 = make_uint4(pkh(b0.x,-b0.y), pkh(b0.y,b0.x), pkh(b1.x,-b1.y), pkh(b1.y,b1.x));
        r.D1 = make_uint4(pkh(b2.x,-b2.y), pkh(b2.y,b2.x), pkh(b3.x,-b3.y), pkh(b3.y,b3.x));
    }
    return r;
}

// lane l = (col = l&15, kb = l>>4): computes P[c = 4*kb+j][pixel col] for j=0..3
// = its MFMA B-fragment directly in registers. Recon via v_dot2_f32_f16.
// [R12 passing structure; HPB row-pairs per block to amortize per-block setup
//  (fragment build, launch overhead) and cut grid 8192 -> 2048 co-resident blocks]
template <bool TR>
__global__ __launch_bounds__(256, 4)
void fused_kernel(const float* __restrict__ base, const float* __restrict__ mod_u,
                  const float* __restrict__ mod_v, const float* __restrict__ del_u,
                  const float* __restrict__ del_v, const float* __restrict__ exp_base,
                  const float* __restrict__ exp_mod, const float* __restrict__ exp_del,
                  const float* __restrict__ bias_, const float* __restrict__ scale_,
                  const float* __restrict__ coef, float* __restrict__ out,
                  const uint32_t* __restrict__ mvT2, const uint32_t* __restrict__ dvT2)
{
    __shared__ uint4 uA16[NC][2][2];   // mod_u packed f16 (ur,ui)/rank; 1 KB; slot ^= (c>>2)&1
    __shared__ uint4 uD16[NC][2];      // del_u packed f16; 512 B

    const int tid  = threadIdx.x;
    const int lane = tid & 63;
    const int wv   = tid >> 6;
    const int col  = lane & 15;
    const int kb   = lane >> 4;                    // c-block / v-block
    const int bw   = (int)(blockIdx.x & 15);
    const int hp   = (int)(blockIdx.x >> 4);       // [0, 128): group of HPB row-pairs
    const int w    = (bw << 6) | (wv << 4) | col;

    // ---------- per-lane A-fragments + bias-const accumulator seed (h-independent) ----------
    const int vv = col;
    const int c0 = kb << 2;

    const float4 cfa = *reinterpret_cast<const float4*>(coef   + (vv * NC + c0) * 2);
    const float4 cfb = *reinterpret_cast<const float4*>(coef   + (vv * NC + c0) * 2 + 4);
    const float4 sca = *reinterpret_cast<const float4*>(scale_ + c0 * 2);
    const float4 scb = *reinterpret_cast<const float4*>(scale_ + c0 * 2 + 4);
    const float4 bia = *reinterpret_cast<const float4*>(bias_  + c0 * 2);
    const float4 bib = *reinterpret_cast<const float4*>(bias_  + c0 * 2 + 4);

    float c2r0 = cfa.x*sca.x - cfa.y*sca.y, c2i0 = cfa.x*sca.y + cfa.y*sca.x;
    float c2r1 = cfa.z*sca.z - cfa.w*sca.w, c2i1 = cfa.z*sca.w + cfa.w*sca.z;
    float c2r2 = cfb.x*scb.x - cfb.y*scb.y, c2i2 = cfb.x*scb.y + cfb.y*scb.x;
    float c2r3 = cfb.z*scb.z - cfb.w*scb.w, c2i3 = cfb.z*scb.w + cfb.w*scb.z;

    const f16x4 Ar = mk4(pkh(c2r0, c2r1), pkh(c2r2, c2r3));
    const f16x4 Ai = mk4(pkh(c2i0, c2i1), pkh(c2i2, c2i3));
    const f16x4 An = mk4(pkh(-c2i0, -c2i1), pkh(-c2i2, -c2i3));

    const f16x4 Kr = mk4(pkh(cfa.x, cfa.z), pkh(cfb.x, cfb.z));
    const f16x4 Ki = mk4(pkh(cfa.y, cfa.w), pkh(cfb.y, cfb.w));
    const f16x4 Kn = mk4(pkh(-cfa.y, -cfa.w), pkh(-cfb.y, -cfb.w));

    const f16x4 Bbr = mk4(pkh(bia.x, bia.z), pkh(bib.x, bib.z));
    const f16x4 Bbi = mk4(pkh(bia.y, bia.w), pkh(bib.y, bib.w));

    const f32x4 zero4 = {0.f, 0.f, 0.f, 0.f};
    const f32x4 cr4 = MFMA16(Kr, Bbr, MFMA16(Kn, Bbi, zero4));
    const f32x4 ci4 = MFMA16(Ki, Bbr, MFMA16(Kr, Bbi, zero4));

    const float ebr = exp_base[0], ebi = exp_base[1];
    const float Ab = 0.5f * ebr, Bb = ebi * K_B, Cb = ebr, Db = ebi * K_D;

    float2* outp = reinterpret_cast<float2*>(out);

    #pragma unroll 1
    for (int it = 0; it < HPB; ++it) {
        const int h0 = (hp * HPB + it) * 2;

        // ---------- cooperative preload + f16 pack of u-tables ----------
        __syncthreads();   // previous iteration's reads complete before overwrite
        {
            if (tid < 64) {                            // uA: 16c x 2rr x 2slots(4 ranks)
                const int c = tid >> 2, rr = (tid >> 1) & 1, k = tid & 1;
                const float4 a = *reinterpret_cast<const float4*>(
                    mod_u + ((c * NH) + (h0 + rr)) * (NRM * 2) + k * 8);
                const float4 b = *reinterpret_cast<const float4*>(
                    mod_u + ((c * NH) + (h0 + rr)) * (NRM * 2) + k * 8 + 4);
                uA16[c][rr][k ^ ((c >> 2) & 1)] =
                    make_uint4(pkh(a.x, a.y), pkh(a.z, a.w), pkh(b.x, b.y), pkh(b.z, b.w));
            } else if (tid < 96) {                     // uD: 16c x 2rr (4 ranks)
                const int t = tid - 64;
                const int c = t >> 1, rr = t & 1;
                const float4 a = *reinterpret_cast<const float4*>(
                    del_u + ((c * NH) + (h0 + rr)) * (NRD * 2));
                const float4 b = *reinterpret_cast<const float4*>(
                    del_u + ((c * NH) + (h0 + rr)) * (NRD * 2) + 4);
                uD16[c][rr] =
                    make_uint4(pkh(a.x, a.y), pkh(a.z, a.w), pkh(b.x, b.y), pkh(b.z, b.w));
            }
        }
        __syncthreads();

        // ---------- base contribution in exponent domain, per row ----------
        float berr[2], beir[2];
        {
            const float2 b0 = reinterpret_cast<const float2*>(base)[(h0    ) * NW + w];
            const float2 b1 = reinterpret_cast<const float2*>(base)[(h0 + 1) * NW + w];
            const float L2b0 = __builtin_amdgcn_logf(fmaf(b0.x, b0.x, b0.y * b0.y));
            const float th0  = atan2_rev(b0.y, b0.x);
            const float L2b1 = __builtin_amdgcn_logf(fmaf(b1.x, b1.x, b1.y * b1.y));
            const float th1  = atan2_rev(b1.y, b1.x);
            berr[0] = fmaf(Ab, L2b0, -Bb * th0);
            beir[0] = fmaf(Cb, th0,   Db * L2b0);
            berr[1] = fmaf(Ab, L2b1, -Bb * th1);
            beir[1] = fmaf(Cb, th1,   Db * L2b1);
        }

        // ---------- main loop: this lane's 4 c-values = its B-fragment ----------
        float Pr[2][4], Pi[2][4];

        #pragma unroll
        for (int j = 0; j < 4; ++j) {
            const int c = c0 | j;
            const V6h cur = load_vh<TR>(mvT2, dvT2, mod_v, del_v, c, w);

            const float2 em = reinterpret_cast<const float2*>(exp_mod)[c];
            const float2 ed = reinterpret_cast<const float2*>(exp_del)[c];
            const float kmA = 0.5f * em.x, kmB = em.y * K_B, kmC = em.x, kmD = em.y * K_D;
            const float kdA = 0.5f * ed.x, kdB = ed.y * K_B, kdC = ed.x, kdD = ed.y * K_D;

            #pragma unroll
            for (int rr = 0; rr < 2; ++rr) {
                const uint4 qa0 = uA16[c][rr][0 ^ ((c >> 2) & 1)];   // ranks 0-3
                const uint4 qa1 = uA16[c][rr][1 ^ ((c >> 2) & 1)];   // ranks 4-7
                const uint4 qd  = uD16[c][rr];                       // del ranks 0-3

                float tr = 0.f, ti = 0.f;
                DOT2(tr, qa0.x, cur.L0.x); DOT2(ti, qa0.x, cur.L0.y);
                DOT2(tr, qa0.y, cur.L0.z); DOT2(ti, qa0.y, cur.L0.w);
                DOT2(tr, qa0.z, cur.L1.x); DOT2(ti, qa0.z, cur.L1.y);
                DOT2(tr, qa0.w, cur.L1.z); DOT2(ti, qa0.w, cur.L1.w);
                DOT2(tr, qa1.x, cur.L2.x); DOT2(ti, qa1.x, cur.L2.y);
                DOT2(tr, qa1.y, cur.L2.z); DOT2(ti, qa1.y, cur.L2.w);
                DOT2(tr, qa1.z, cur.L3.x); DOT2(ti, qa1.z, cur.L3.y);
                DOT2(tr, qa1.w, cur.L3.z); DOT2(ti, qa1.w, cur.L3.w);

                float dr = 0.f, di = 0.f;
                DOT2(dr, qd.x, cur.D0.x); DOT2(di, qd.x, cur.D0.y);
                DOT2(dr, qd.y, cur.D0.z); DOT2(di, qd.y, cur.D0.w);
                DOT2(dr, qd.z, cur.D1.x); DOT2(di, qd.z, cur.D1.y);
                DOT2(dr, qd.w, cur.D1.z); DOT2(di, qd.w, cur.D1.w);

                // mod power, base-folded: pb*pm = exp2(er2)·cis(2pi·eir)
                const float L2m = __builtin_amdgcn_logf(fmaf(tr, tr, ti * ti));
                const float thm = atan2_rev(ti, tr);
                const float er2 = fmaf(kmA, L2m, fmaf(-kmB, thm, berr[rr]));
                const float eir = fmaf(kmC, thm, fmaf(kmD, L2m, beir[rr]));
                const float mm  = __builtin_amdgcn_exp2f(er2);
                const float fm  = __builtin_amdgcn_fractf(eir);
                const float cv  = __builtin_amdgcn_cosf(fm);
                const float sv  = __builtin_amdgcn_sinf(fm);

                // del power
                const float L2d = __builtin_amdgcn_logf(fmaf(dr, dr, di * di));
                const float thd = atan2_rev(di, dr);
                const float er2d = fmaf(kdA, L2d, -kdB * thd);
                const float eird = fmaf(kdC, thd,  kdD * L2d);
                const float md  = __builtin_amdgcn_exp2f(er2d);
                const float fd  = __builtin_amdgcn_fractf(eird);
                const float cvd = __builtin_amdgcn_cosf(fd);
                const float svd = __builtin_amdgcn_sinf(fd);

                Pr[rr][j] = fmaf(mm, cv, md * cvd);
                Pi[rr][j] = fmaf(mm, sv, md * svd);
            }
        }

        // ---------- MFMA einsum straight from registers ----------
        #pragma unroll
        for (int rr = 0; rr < 2; ++rr) {
            const f16x4 Brf = mk4(pkh(Pr[rr][0], Pr[rr][1]), pkh(Pr[rr][2], Pr[rr][3]));
            const f16x4 Bif = mk4(pkh(Pi[rr][0], Pi[rr][1]), pkh(Pi[rr][2], Pi[rr][3]));
            const f32x4 Dr = MFMA16(Ar, Brf, MFMA16(An, Bif, cr4));
            const f32x4 Di = MFMA16(Ai, Brf, MFMA16(Ar, Bif, ci4));
            const int bidx = (h0 + rr) * NW + w;
            #pragma unroll
            for (int jj = 0; jj < 4; ++jj) {
                const int v = (kb << 2) + jj;
                outp[v * (NH * NW) + bidx] = make_float2(Dr[jj], Di[jj]);
            }
        }
    }
}

extern "C" void kernel_launch(void* const* d_in, const int* in_sizes, int n_in,
                              void* d_out, int out_size, void* d_ws, size_t ws_size,
                              hipStream_t stream) {
    const float* base     = (const float*)d_in[0];
    const float* mod_u    = (const float*)d_in[1];
    const float* mod_v    = (const float*)d_in[2];
    const float* del_u    = (const float*)d_in[3];
    const float* del_v    = (const float*)d_in[4];
    const float* exp_base = (const float*)d_in[5];
    const float* exp_mod  = (const float*)d_in[6];
    const float* exp_del  = (const float*)d_in[7];
    const float* bias_    = (const float*)d_in[8];
    const float* scale_   = (const float*)d_in[9];
    const float* coef     = (const float*)d_in[10];
    float* outp = (float*)d_out;

    const int blocks = (NH / 2 / HPB) * (NW / 64);         // 128 * 16 = 2048
    const size_t mvT2_u32 = (size_t)NC * NW * NRM * 2;     // 1 MB
    const size_t dvT2_u32 = (size_t)NC * NW * NRD * 2;     // 0.5 MB
    const size_t need = (mvT2_u32 + dvT2_u32) * sizeof(uint32_t);

    if (ws_size >= need) {
        uint32_t* mvT2 = (uint32_t*)d_ws;
        uint32_t* dvT2 = mvT2 + mvT2_u32;
        const int rp_items = NC * NRM * NW + NC * NRD * NW;     // 196608
        repack_v<<<rp_items / 256, 256, 0, stream>>>(mod_v, del_v, mvT2, dvT2);
        fused_kernel<true><<<blocks, 256, 0, stream>>>(base, mod_u, mod_v, del_u, del_v,
                                                       exp_base, exp_mod, exp_del,
                                                       bias_, scale_, coef, outp, mvT2, dvT2);
    } else {
        fused_kernel<false><<<blocks, 256, 0, stream>>>(base, mod_u, mod_v, del_u, del_v,
                                                        exp_base, exp_mod, exp_del,
                                                        bias_, scale_, coef, outp,
                                                        (const uint32_t*)nullptr, (const uint32_t*)nullptr);
    }
}

// Round 18
// 83.499 us; speedup vs baseline: 1.4231x; 1.0873x over previous
//
#include <hip/hip_runtime.h>
#include <stdint.h>

#define NV 16
#define NC 16
#define NH 1024
#define NW 1024
#define NRM 8
#define NRD 4

typedef __attribute__((ext_vector_type(4))) _Float16 f16x4;
typedef __attribute__((ext_vector_type(2))) __fp16 fp16x2_raw;
typedef __attribute__((ext_vector_type(4))) float f32x4;

#define MFMA16(a, b, c) __builtin_amdgcn_mfma_f32_16x16x16f16((a), (b), (c), 0, 0, 0)

// f32 pair -> packed f16 (RTZ)
__device__ __forceinline__ uint32_t pkh(float a, float b) {
    fp16x2_raw h = __builtin_amdgcn_cvt_pkrtz(a, b);
    return __builtin_bit_cast(uint32_t, h);
}

__device__ __forceinline__ f16x4 mk4(uint32_t lo, uint32_t hi) {
    union { uint32_t u[2]; f16x4 v; } t;
    t.u[0] = lo; t.u[1] = hi;
    return t.v;
}

// acc += dot2(f16x2(u), f16x2(v))  -- full-rate f16 MAC pair with f32 accumulate
#define DOT2(acc, u, v) \
    asm("v_dot2_f32_f16 %0, %1, %2, %0" : "+v"(acc) : "v"(u), "v"(v))

// atan2 emitting REVOLUTIONS (atan2/2pi)
__device__ __forceinline__ float atan2_rev(float y, float x) {
    float ax = fabsf(x), ay = fabsf(y);
    float mx = fmaxf(ax, ay), mn = fminf(ax, ay);
    float a = mn * __builtin_amdgcn_rcpf(mx);
    float s = a * a;
    float p =              -0.00186549f;
    p = fmaf(p, s,  0.00838003f);
    p = fmaf(p, s, -0.01852970f);
    p = fmaf(p, s,  0.03080340f);
    p = fmaf(p, s, -0.05294381f);
    p = fmaf(p, s,  0.15915132f);
    p = p * a;
    float t = (ay > ax) ? (0.25f - p) : p;
    t = (x < 0.0f) ? (0.5f - t) : t;
    return (y < 0.0f) ? -t : t;
}

// exponent-domain constants: A=0.5*wr  B=wi*2pi*log2e  C=wr  D=wi*ln2/(4pi)
#define K_B 9.06472028f
#define K_D 0.05516054f

// -------- pre-pass: repack mod_v/del_v to [c][w][r] dual-form f16 --------
__global__ __launch_bounds__(256)
void repack_v(const float* __restrict__ mod_v, const float* __restrict__ del_v,
              uint32_t* __restrict__ mvT2, uint32_t* __restrict__ dvT2)
{
    const int idx = blockIdx.x * 256 + threadIdx.x;
    if (idx < NC * NRM * NW) {                       // 131072 mod items
        const int c = idx >> 13, r = (idx >> 10) & 7, w = idx & 1023;
        const float2 v = reinterpret_cast<const float2*>(mod_v)[(c * NRM + r) * NW + w];
        uint2* dst = reinterpret_cast<uint2*>(mvT2) + (c * NW + w) * NRM + r;
        *dst = make_uint2(pkh(v.x, -v.y), pkh(v.y, v.x));
    } else {                                         // 65536 del items
        const int t = idx - NC * NRM * NW;
        const int c = t >> 12, r = (t >> 10) & 3, w = t & 1023;
        const float2 v = reinterpret_cast<const float2*>(del_v)[(c * NRD + r) * NW + w];
        uint2* dst = reinterpret_cast<uint2*>(dvT2) + (c * NW + w) * NRD + r;
        *dst = make_uint2(pkh(v.x, -v.y), pkh(v.y, v.x));
    }
}

struct V6h { uint4 L0, L1, L2, L3, D0, D1; };   // mod ranks 0-7, del ranks 0-3 (dual-form f16)

template <bool TR>
__device__ __forceinline__ V6h load_vh(const uint32_t* __restrict__ mvT2,
                                       const uint32_t* __restrict__ dvT2,
                                       const float* __restrict__ mod_v,
                                       const float* __restrict__ del_v,
                                       int c, int w)
{
    V6h r;
    if (TR) {
        const uint4* mp = reinterpret_cast<const uint4*>(mvT2) + (c * NW + w) * 4;
        r.L0 = mp[0]; r.L1 = mp[1]; r.L2 = mp[2]; r.L3 = mp[3];
        const uint4* dp = reinterpret_cast<const uint4*>(dvT2) + (c * NW + w) * 2;
        r.D0 = dp[0]; r.D1 = dp[1];
    } else {
        const float2* m = reinterpret_cast<const float2*>(mod_v) + c * NRM * NW + w;
        float2 a0 = m[0], a1 = m[NW], a2 = m[2*NW], a3 = m[3*NW];
        float2 a4 = m[4*NW], a5 = m[5*NW], a6 = m[6*NW], a7 = m[7*NW];
        r.L0 = make_uint4(pkh(a0.x,-a0.y), pkh(a0.y,a0.x), pkh(a1.x,-a1.y), pkh(a1.y,a1.x));
        r.L1 = make_uint4(pkh(a2.x,-a2.y), pkh(a2.y,a2.x), pkh(a3.x,-a3.y), pkh(a3.y,a3.x));
        r.L2 = make_uint4(pkh(a4.x,-a4.y), pkh(a4.y,a4.x), pkh(a5.x,-a5.y), pkh(a5.y,a5.x));
        r.L3 = make_uint4(pkh(a6.x,-a6.y), pkh(a6.y,a6.x), pkh(a7.x,-a7.y), pkh(a7.y,a7.x));
        const float2* d = reinterpret_cast<const float2*>(del_v) + c * NRD * NW + w;
        float2 b0 = d[0], b1 = d[NW], b2 = d[2*NW], b3 = d[3*NW];
        r.D0 = make_uint4(pkh(b0.x,-b0.y), pkh(b0.y,b0.x), pkh(b1.x,-b1.y), pkh(b1.y,b1.x));
        r.D1 = make_uint4(pkh(b2.x,-b2.y), pkh(b2.y,b2.x), pkh(b3.x,-b3.y), pkh(b3.y,b3.x));
    }
    return r;
}

// lane l = (col = l&15, kb = l>>4): computes P[c = 4*kb+j][pixel col] for j=0..3
// = its MFMA B-fragment directly in registers. Recon via v_dot2_f32_f16.
// [R12 verified-best structure: ROWS=2, 8192 blocks, 44 VGPR, 83.6 us]
template <bool TR>
__global__ __launch_bounds__(256, 4)
void fused_kernel(const float* __restrict__ base, const float* __restrict__ mod_u,
                  const float* __restrict__ mod_v, const float* __restrict__ del_u,
                  const float* __restrict__ del_v, const float* __restrict__ exp_base,
                  const float* __restrict__ exp_mod, const float* __restrict__ exp_del,
                  const float* __restrict__ bias_, const float* __restrict__ scale_,
                  const float* __restrict__ coef, float* __restrict__ out,
                  const uint32_t* __restrict__ mvT2, const uint32_t* __restrict__ dvT2)
{
    __shared__ uint4 uA16[NC][2][2];   // mod_u packed f16 (ur,ui)/rank; 1 KB; slot ^= (c>>2)&1
    __shared__ uint4 uD16[NC][2];      // del_u packed f16; 512 B

    const int tid  = threadIdx.x;
    const int lane = tid & 63;
    const int wv   = tid >> 6;
    const int col  = lane & 15;
    const int kb   = lane >> 4;                    // c-block / v-block
    const int bw   = (int)(blockIdx.x & 15);
    const int hp   = (int)(blockIdx.x >> 4);
    const int h0   = hp * 2;
    const int w    = (bw << 6) | (wv << 4) | col;

    // ---------- cooperative preload + f16 pack of u-tables ----------
    {
        if (tid < 64) {                            // uA: 16c x 2rr x 2slots(4 ranks)
            const int c = tid >> 2, rr = (tid >> 1) & 1, k = tid & 1;
            const float4 a = *reinterpret_cast<const float4*>(
                mod_u + ((c * NH) + (h0 + rr)) * (NRM * 2) + k * 8);
            const float4 b = *reinterpret_cast<const float4*>(
                mod_u + ((c * NH) + (h0 + rr)) * (NRM * 2) + k * 8 + 4);
            uA16[c][rr][k ^ ((c >> 2) & 1)] =
                make_uint4(pkh(a.x, a.y), pkh(a.z, a.w), pkh(b.x, b.y), pkh(b.z, b.w));
        } else if (tid < 96) {                     // uD: 16c x 2rr (4 ranks)
            const int t = tid - 64;
            const int c = t >> 1, rr = t & 1;
            const float4 a = *reinterpret_cast<const float4*>(
                del_u + ((c * NH) + (h0 + rr)) * (NRD * 2));
            const float4 b = *reinterpret_cast<const float4*>(
                del_u + ((c * NH) + (h0 + rr)) * (NRD * 2) + 4);
            uD16[c][rr] =
                make_uint4(pkh(a.x, a.y), pkh(a.z, a.w), pkh(b.x, b.y), pkh(b.z, b.w));
        }
    }
    __syncthreads();

    // ---------- per-lane A-fragments + bias-const accumulator seed ----------
    const int vv = col;
    const int c0 = kb << 2;

    const float4 cfa = *reinterpret_cast<const float4*>(coef   + (vv * NC + c0) * 2);
    const float4 cfb = *reinterpret_cast<const float4*>(coef   + (vv * NC + c0) * 2 + 4);
    const float4 sca = *reinterpret_cast<const float4*>(scale_ + c0 * 2);
    const float4 scb = *reinterpret_cast<const float4*>(scale_ + c0 * 2 + 4);
    const float4 bia = *reinterpret_cast<const float4*>(bias_  + c0 * 2);
    const float4 bib = *reinterpret_cast<const float4*>(bias_  + c0 * 2 + 4);

    float c2r0 = cfa.x*sca.x - cfa.y*sca.y, c2i0 = cfa.x*sca.y + cfa.y*sca.x;
    float c2r1 = cfa.z*sca.z - cfa.w*sca.w, c2i1 = cfa.z*sca.w + cfa.w*sca.z;
    float c2r2 = cfb.x*scb.x - cfb.y*scb.y, c2i2 = cfb.x*scb.y + cfb.y*scb.x;
    float c2r3 = cfb.z*scb.z - cfb.w*scb.w, c2i3 = cfb.z*scb.w + cfb.w*scb.z;

    const f16x4 Ar = mk4(pkh(c2r0, c2r1), pkh(c2r2, c2r3));
    const f16x4 Ai = mk4(pkh(c2i0, c2i1), pkh(c2i2, c2i3));
    const f16x4 An = mk4(pkh(-c2i0, -c2i1), pkh(-c2i2, -c2i3));

    const f16x4 Kr = mk4(pkh(cfa.x, cfa.z), pkh(cfb.x, cfb.z));
    const f16x4 Ki = mk4(pkh(cfa.y, cfa.w), pkh(cfb.y, cfb.w));
    const f16x4 Kn = mk4(pkh(-cfa.y, -cfa.w), pkh(-cfb.y, -cfb.w));

    const f16x4 Bbr = mk4(pkh(bia.x, bia.z), pkh(bib.x, bib.z));
    const f16x4 Bbi = mk4(pkh(bia.y, bia.w), pkh(bib.y, bib.w));

    const f32x4 zero4 = {0.f, 0.f, 0.f, 0.f};
    const f32x4 cr4 = MFMA16(Kr, Bbr, MFMA16(Kn, Bbi, zero4));
    const f32x4 ci4 = MFMA16(Ki, Bbr, MFMA16(Kr, Bbi, zero4));

    // ---------- base contribution in exponent domain, per row ----------
    const float ebr = exp_base[0], ebi = exp_base[1];
    const float Ab = 0.5f * ebr, Bb = ebi * K_B, Cb = ebr, Db = ebi * K_D;
    float berr[2], beir[2];
    {
        const float2 b0 = reinterpret_cast<const float2*>(base)[(h0    ) * NW + w];
        const float2 b1 = reinterpret_cast<const float2*>(base)[(h0 + 1) * NW + w];
        const float L2b0 = __builtin_amdgcn_logf(fmaf(b0.x, b0.x, b0.y * b0.y));
        const float th0  = atan2_rev(b0.y, b0.x);
        const float L2b1 = __builtin_amdgcn_logf(fmaf(b1.x, b1.x, b1.y * b1.y));
        const float th1  = atan2_rev(b1.y, b1.x);
        berr[0] = fmaf(Ab, L2b0, -Bb * th0);
        beir[0] = fmaf(Cb, th0,   Db * L2b0);
        berr[1] = fmaf(Ab, L2b1, -Bb * th1);
        beir[1] = fmaf(Cb, th1,   Db * L2b1);
    }

    // ---------- main loop: this lane's 4 c-values = its B-fragment ----------
    float Pr[2][4], Pi[2][4];

    #pragma unroll
    for (int j = 0; j < 4; ++j) {
        const int c = c0 | j;
        const V6h cur = load_vh<TR>(mvT2, dvT2, mod_v, del_v, c, w);

        const float2 em = reinterpret_cast<const float2*>(exp_mod)[c];
        const float2 ed = reinterpret_cast<const float2*>(exp_del)[c];
        const float kmA = 0.5f * em.x, kmB = em.y * K_B, kmC = em.x, kmD = em.y * K_D;
        const float kdA = 0.5f * ed.x, kdB = ed.y * K_B, kdC = ed.x, kdD = ed.y * K_D;

        #pragma unroll
        for (int rr = 0; rr < 2; ++rr) {
            const uint4 qa0 = uA16[c][rr][0 ^ ((c >> 2) & 1)];   // ranks 0-3
            const uint4 qa1 = uA16[c][rr][1 ^ ((c >> 2) & 1)];   // ranks 4-7
            const uint4 qd  = uD16[c][rr];                       // del ranks 0-3

            float tr = 0.f, ti = 0.f;
            DOT2(tr, qa0.x, cur.L0.x); DOT2(ti, qa0.x, cur.L0.y);
            DOT2(tr, qa0.y, cur.L0.z); DOT2(ti, qa0.y, cur.L0.w);
            DOT2(tr, qa0.z, cur.L1.x); DOT2(ti, qa0.z, cur.L1.y);
            DOT2(tr, qa0.w, cur.L1.z); DOT2(ti, qa0.w, cur.L1.w);
            DOT2(tr, qa1.x, cur.L2.x); DOT2(ti, qa1.x, cur.L2.y);
            DOT2(tr, qa1.y, cur.L2.z); DOT2(ti, qa1.y, cur.L2.w);
            DOT2(tr, qa1.z, cur.L3.x); DOT2(ti, qa1.z, cur.L3.y);
            DOT2(tr, qa1.w, cur.L3.z); DOT2(ti, qa1.w, cur.L3.w);

            float dr = 0.f, di = 0.f;
            DOT2(dr, qd.x, cur.D0.x); DOT2(di, qd.x, cur.D0.y);
            DOT2(dr, qd.y, cur.D0.z); DOT2(di, qd.y, cur.D0.w);
            DOT2(dr, qd.z, cur.D1.x); DOT2(di, qd.z, cur.D1.y);
            DOT2(dr, qd.w, cur.D1.z); DOT2(di, qd.w, cur.D1.w);

            // mod power, base-folded: pb*pm = exp2(er2)·cis(2pi·eir)
            const float L2m = __builtin_amdgcn_logf(fmaf(tr, tr, ti * ti));
            const float thm = atan2_rev(ti, tr);
            const float er2 = fmaf(kmA, L2m, fmaf(-kmB, thm, berr[rr]));
            const float eir = fmaf(kmC, thm, fmaf(kmD, L2m, beir[rr]));
            const float mm  = __builtin_amdgcn_exp2f(er2);
            const float fm  = __builtin_amdgcn_fractf(eir);
            const float cv  = __builtin_amdgcn_cosf(fm);
            const float sv  = __builtin_amdgcn_sinf(fm);

            // del power
            const float L2d = __builtin_amdgcn_logf(fmaf(dr, dr, di * di));
            const float thd = atan2_rev(di, dr);
            const float er2d = fmaf(kdA, L2d, -kdB * thd);
            const float eird = fmaf(kdC, thd,  kdD * L2d);
            const float md  = __builtin_amdgcn_exp2f(er2d);
            const float fd  = __builtin_amdgcn_fractf(eird);
            const float cvd = __builtin_amdgcn_cosf(fd);
            const float svd = __builtin_amdgcn_sinf(fd);

            Pr[rr][j] = fmaf(mm, cv, md * cvd);
            Pi[rr][j] = fmaf(mm, sv, md * svd);
        }
    }

    // ---------- MFMA einsum straight from registers ----------
    float2* outp = reinterpret_cast<float2*>(out);
    #pragma unroll
    for (int rr = 0; rr < 2; ++rr) {
        const f16x4 Brf = mk4(pkh(Pr[rr][0], Pr[rr][1]), pkh(Pr[rr][2], Pr[rr][3]));
        const f16x4 Bif = mk4(pkh(Pi[rr][0], Pi[rr][1]), pkh(Pi[rr][2], Pi[rr][3]));
        const f32x4 Dr = MFMA16(Ar, Brf, MFMA16(An, Bif, cr4));
        const f32x4 Di = MFMA16(Ai, Brf, MFMA16(Ar, Bif, ci4));
        const int bidx = (h0 + rr) * NW + w;
        #pragma unroll
        for (int jj = 0; jj < 4; ++jj) {
            const int v = (kb << 2) + jj;
            outp[v * (NH * NW) + bidx] = make_float2(Dr[jj], Di[jj]);
        }
    }
}

extern "C" void kernel_launch(void* const* d_in, const int* in_sizes, int n_in,
                              void* d_out, int out_size, void* d_ws, size_t ws_size,
                              hipStream_t stream) {
    const float* base     = (const float*)d_in[0];
    const float* mod_u    = (const float*)d_in[1];
    const float* mod_v    = (const float*)d_in[2];
    const float* del_u    = (const float*)d_in[3];
    const float* del_v    = (const float*)d_in[4];
    const float* exp_base = (const float*)d_in[5];
    const float* exp_mod  = (const float*)d_in[6];
    const float* exp_del  = (const float*)d_in[7];
    const float* bias_    = (const float*)d_in[8];
    const float* scale_   = (const float*)d_in[9];
    const float* coef     = (const float*)d_in[10];
    float* outp = (float*)d_out;

    const int blocks = (NH / 2) * (NW / 64);               // 8192
    const size_t mvT2_u32 = (size_t)NC * NW * NRM * 2;     // 1 MB
    const size_t dvT2_u32 = (size_t)NC * NW * NRD * 2;     // 0.5 MB
    const size_t need = (mvT2_u32 + dvT2_u32) * sizeof(uint32_t);

    if (ws_size >= need) {
        uint32_t* mvT2 = (uint32_t*)d_ws;
        uint32_t* dvT2 = mvT2 + mvT2_u32;
        const int rp_items = NC * NRM * NW + NC * NRD * NW;     // 196608
        repack_v<<<rp_items / 256, 256, 0, stream>>>(mod_v, del_v, mvT2, dvT2);
        fused_kernel<true><<<blocks, 256, 0, stream>>>(base, mod_u, mod_v, del_u, del_v,
                                                       exp_base, exp_mod, exp_del,
                                                       bias_, scale_, coef, outp, mvT2, dvT2);
    } else {
        fused_kernel<false><<<blocks, 256, 0, stream>>>(base, mod_u, mod_v, del_u, del_v,
                                                        exp_base, exp_mod, exp_del,
                                                        bias_, scale_, coef, outp,
                                                        (const uint32_t*)nullptr, (const uint32_t*)nullptr);
    }
}